// Round 8
// baseline (224.834 us; speedup 1.0000x reference)
//
#include <hip/hip_runtime.h>
#include <hip/hip_fp16.h>

#define N_SRC 16384
#define N_TGT 65536
#define KNN 8
#define CMV 16
#define CSKIP 2
#define SSC 32
#define HID 64
#define MVD 16

#define OUT_MV_ELEMS (N_TGT * CMV * MVD)   // 16777216 floats
// ws layout (float offsets):
#define PROJ_OFFSET 512                                  // fp16 proj: N_SRC x 256 h (8 MB)
#define WN_OFFSET   (PROJ_OFFSET + (N_SRC * 256 / 2))    // f32 wn[E] (2 MB)
#define P1_OFFSET   (WN_OFFSET + N_TGT * KNN)            // fp16 P1[s][64] = sc_src@W1top (2 MB)
#define HSK_OFFSET  (P1_OFFSET + (N_SRC * HID / 2))      // fp16 HSK[t][64] = skip@W1bot + b1 (8 MB)
#define WS_END      (HSK_OFFSET + (N_TGT * HID / 2))

typedef float vf4 __attribute__((ext_vector_type(4)));

__device__ __forceinline__ float4 nt_load4(const float* p) {
    vf4 v = __builtin_nontemporal_load((const vf4*)p);
    return make_float4(v.x, v.y, v.z, v.w);
}
__device__ __forceinline__ void nt_store4(float* p, float4 o) {
    vf4 v; v.x = o.x; v.y = o.y; v.z = o.z; v.w = o.w;
    __builtin_nontemporal_store(v, (vf4*)p);
}

__device__ __forceinline__ float gelu_tanh(float x) {
    const float k0 = 0.7978845608028654f;  // sqrt(2/pi)
    const float k1 = 0.044715f;
    float yy = k0 * (x + k1 * x * x * x);
    return 0.5f * x * (1.0f + tanhf(yy));
}

__device__ __forceinline__ float h2f(unsigned short u) {
    __half h = __ushort_as_half(u);
    return __half2float(h);
}

// ---------------------------------------------------------------------------
// Kernel A (preprocessing, all linear-algebra folds):
//  (W)  wn[E]: normalized IDW weights, one thread per target.
//  (P)  proj[s][d][i] = sum_c mv_src[s][c][i] * W_eff[c][d], fp16
//       (W_eff = W1_mv @ W2_mv; the mv path is fully linear).
//  (P1) P1[s][h] = sum_{c<32} sc_src[s][c] * W1_s[c][h], fp16
//       (GEMM1's interp half commutes with interpolation).
//  (HSK) HSK[t][h] = b1[h] + sum_{c<32} sc_skip[t][c] * W1_s[32+c][h], fp16.
//  Block 0 writes skip rows of W_eff to ws[0..31].
// ---------------------------------------------------------------------------
__global__ __launch_bounds__(256) void kA_preproject(
        const float* __restrict__ mv_src,
        const float* __restrict__ sc_src,
        const float* __restrict__ sc_skip,
        const float* __restrict__ pos_src,
        const float* __restrict__ pos_tgt,
        const int*   __restrict__ isrc,
        const float* __restrict__ W1_mv,
        const float* __restrict__ W2_mv,
        const float* __restrict__ W1_s,
        const float* __restrict__ b1_s,
        float* __restrict__ ws) {
    __shared__ float sWeff[CMV][MVD];
    int tid = threadIdx.x;
    {
        int c = tid >> 4, d = tid & 15;
        float a = 0.f;
        #pragma unroll 8
        for (int h = 0; h < HID; ++h)
            a = fmaf(W1_mv[c * HID + h], W2_mv[h * MVD + d], a);
        sWeff[c][d] = a;
    }
    if (blockIdx.x == 0 && tid < 32) {
        int j = tid >> 4, d = tid & 15;
        float a = 0.f;
        #pragma unroll 8
        for (int h = 0; h < HID; ++h)
            a = fmaf(W1_mv[(CMV + j) * HID + h], W2_mv[h * MVD + d], a);
        ws[j * MVD + d] = a;
    }

    int nthreads = gridDim.x * 256;

    // --- phase W: IDW weights ---
    for (int t = blockIdx.x * 256 + tid; t < N_TGT; t += nthreads) {
        float ptx = pos_tgt[t * 3 + 0], pty = pos_tgt[t * 3 + 1], ptz = pos_tgt[t * 3 + 2];
        int4 e0 = *(const int4*)(isrc + t * KNN);
        int4 e1 = *(const int4*)(isrc + t * KNN + 4);
        int sk[KNN] = {e0.x, e0.y, e0.z, e0.w, e1.x, e1.y, e1.z, e1.w};
        float wk[KNN];
        float den = 0.f;
        #pragma unroll
        for (int k = 0; k < KNN; ++k) {
            int s = sk[k];
            float dx = pos_src[s * 3 + 0] - ptx;
            float dy = pos_src[s * 3 + 1] - pty;
            float dz = pos_src[s * 3 + 2] - ptz;
            float d2 = fmaxf(dx * dx + dy * dy + dz * dz, 1e-16f);
            wk[k] = 1.0f / d2;
            den += wk[k];
        }
        float invd = 1.0f / den;
        float* wn = ws + WN_OFFSET;
        float4 a = make_float4(wk[0] * invd, wk[1] * invd, wk[2] * invd, wk[3] * invd);
        float4 b = make_float4(wk[4] * invd, wk[5] * invd, wk[6] * invd, wk[7] * invd);
        *(float4*)(wn + (size_t)t * 8)     = a;
        *(float4*)(wn + (size_t)t * 8 + 4) = b;
    }
    __syncthreads();

    int lane = tid & 63;
    int wid = (int)((blockIdx.x * 256 + tid) >> 6);
    int nw  = nthreads >> 6;

    // --- phase P: mv projection table ---
    {
        int d = lane >> 2, q = lane & 3;
        float wcol[CMV];
        #pragma unroll
        for (int c = 0; c < CMV; ++c) wcol[c] = sWeff[c][d];
        __half* proj = (__half*)(ws + PROJ_OFFSET);
        for (int s = wid; s < N_SRC; s += nw) {
            const float* row = mv_src + (size_t)s * 256;
            float4 o = make_float4(0.f, 0.f, 0.f, 0.f);
            #pragma unroll
            for (int c = 0; c < CMV; ++c) {
                float4 v = *(const float4*)(row + c * 16 + q * 4);
                o.x = fmaf(v.x, wcol[c], o.x);
                o.y = fmaf(v.y, wcol[c], o.y);
                o.z = fmaf(v.z, wcol[c], o.z);
                o.w = fmaf(v.w, wcol[c], o.w);
            }
            union { __half2 h[2]; uint2 u; } P;
            P.h[0] = __floats2half2_rn(o.x, o.y);
            P.h[1] = __floats2half2_rn(o.z, o.w);
            *(uint2*)(proj + (size_t)s * 256 + lane * 4) = P.u;
        }
    }

    // --- phase P1: sc projection table (lane = h) ---
    {
        unsigned short* P1 = (unsigned short*)(ws + P1_OFFSET);
        for (int s = wid; s < N_SRC; s += nw) {
            float a = 0.f;
            #pragma unroll 8
            for (int c = 0; c < SSC; ++c)
                a = fmaf(sc_src[(size_t)s * SSC + c], W1_s[c * HID + lane], a);
            P1[(size_t)s * HID + lane] = __half_as_ushort(__float2half_rn(a));
        }
    }

    // --- phase HSK: skip half of GEMM1 + bias (lane = h) ---
    {
        unsigned short* HSK = (unsigned short*)(ws + HSK_OFFSET);
        for (int t = wid; t < N_TGT; t += nw) {
            float a = b1_s[lane];
            #pragma unroll 8
            for (int c = 0; c < SSC; ++c)
                a = fmaf(sc_skip[(size_t)t * SSC + c], W1_s[(SSC + c) * HID + lane], a);
            HSK[(size_t)t * HID + lane] = __half_as_ushort(__float2half_rn(a));
        }
    }
}

// ---------------------------------------------------------------------------
// Fused kernel: every wave handles 2 targets, BOTH paths.
//  mv:  16 gathers (8 B/lane) + skip FMA + NT store  (round-6 structure).
//  sc:  16 P1 gathers (2 B/lane; hides behind the mv gathers) + HSK stream
//       + gelu + GEMM2 via tiny per-wave LDS transpose (34 LDS ops/wave,
//       replacing the old GEMM1 block structure that pinned every CU's LDS
//       pipe for ~35 us).
// ---------------------------------------------------------------------------
__global__ __launch_bounds__(256, 5) void kFused(
        const float* __restrict__ ws,
        const float* __restrict__ mv_skip,
        const int*   __restrict__ isrc,
        const float* __restrict__ W2_s,
        const float* __restrict__ b2_s,
        float* __restrict__ out) {
    __shared__ float sW2T[SSC][65];     // [s][h], stride 65 -> conflict-free
    __shared__ float sb2[SSC];
    __shared__ float sH[4][2][HID];     // per-wave H buffer

    int tid = threadIdx.x;
    for (int e = tid; e < HID * SSC; e += 256) {
        int h = e >> 5, s = e & 31;
        sW2T[s][h] = W2_s[e];
    }
    if (tid < SSC) sb2[tid] = b2_s[tid];
    __syncthreads();

    int lane = tid & 63, wv = tid >> 6;
    int dd = lane >> 2, q = lane & 3;
    float wsk0 = ws[dd], wsk1 = ws[MVD + dd];
    const __half* proj = (const __half*)(ws + PROJ_OFFSET);
    const float*  wn   = ws + WN_OFFSET;
    const unsigned short* P1  = (const unsigned short*)(ws + P1_OFFSET);
    const unsigned short* HSK = (const unsigned short*)(ws + HSK_OFFSET);

    int wid = (int)((blockIdx.x * blockDim.x + tid) >> 6);  // 0..32767
    int t0 = wid * 2;

    // preamble: 16 edges (2 targets), coalesced
    int   src2 = 0; float wn2 = 0.f;
    if (lane < 16) {
        src2 = isrc[(size_t)t0 * KNN + lane];
        wn2  = wn[(size_t)t0 * KNN + lane];
    }

    // streams (issue early)
    float4 u0A = nt_load4(mv_skip + (size_t)t0 * 32 + q * 4);
    float4 u1A = nt_load4(mv_skip + (size_t)t0 * 32 + 16 + q * 4);
    float4 u0B = nt_load4(mv_skip + (size_t)(t0 + 1) * 32 + q * 4);
    float4 u1B = nt_load4(mv_skip + (size_t)(t0 + 1) * 32 + 16 + q * 4);
    unsigned short hsA = HSK[(size_t)t0 * HID + lane];
    unsigned short hsB = HSK[(size_t)(t0 + 1) * HID + lane];

    // gathers: 16 mv rows (8 B/lane) + 16 P1 rows (2 B/lane)
    uint2 g[16];
    unsigned short p[16];
    #pragma unroll
    for (int k = 0; k < 16; ++k) {
        int sk = __builtin_amdgcn_readlane(src2, k);
        g[k] = *(const uint2*)(proj + (size_t)sk * 256 + lane * 4);
        p[k] = P1[(size_t)sk * HID + lane];
    }

    // ---- mv consume ----
    float4 accA = make_float4(0.f, 0.f, 0.f, 0.f);
    float4 accB = make_float4(0.f, 0.f, 0.f, 0.f);
    #pragma unroll
    for (int k = 0; k < KNN; ++k) {
        float wk = __uint_as_float(__builtin_amdgcn_readlane(__float_as_uint(wn2), k));
        union { uint2 u; __half2 h[2]; } P; P.u = g[k];
        float2 lo = __half22float2(P.h[0]);
        float2 hi = __half22float2(P.h[1]);
        accA.x = fmaf(wk, lo.x, accA.x);
        accA.y = fmaf(wk, lo.y, accA.y);
        accA.z = fmaf(wk, hi.x, accA.z);
        accA.w = fmaf(wk, hi.y, accA.w);
    }
    #pragma unroll
    for (int k = 0; k < KNN; ++k) {
        float wk = __uint_as_float(__builtin_amdgcn_readlane(__float_as_uint(wn2), 8 + k));
        union { uint2 u; __half2 h[2]; } P; P.u = g[8 + k];
        float2 lo = __half22float2(P.h[0]);
        float2 hi = __half22float2(P.h[1]);
        accB.x = fmaf(wk, lo.x, accB.x);
        accB.y = fmaf(wk, lo.y, accB.y);
        accB.z = fmaf(wk, hi.x, accB.z);
        accB.w = fmaf(wk, hi.y, accB.w);
    }
    {
        float4 o;
        o.x = accA.x + fmaf(wsk0, u0A.x, wsk1 * u1A.x);
        o.y = accA.y + fmaf(wsk0, u0A.y, wsk1 * u1A.y);
        o.z = accA.z + fmaf(wsk0, u0A.z, wsk1 * u1A.z);
        o.w = accA.w + fmaf(wsk0, u0A.w, wsk1 * u1A.w);
        nt_store4(out + (size_t)t0 * 256 + lane * 4, o);
    }
    {
        float4 o;
        o.x = accB.x + fmaf(wsk0, u0B.x, wsk1 * u1B.x);
        o.y = accB.y + fmaf(wsk0, u0B.y, wsk1 * u1B.y);
        o.z = accB.z + fmaf(wsk0, u0B.z, wsk1 * u1B.z);
        o.w = accB.w + fmaf(wsk0, u0B.w, wsk1 * u1B.w);
        nt_store4(out + (size_t)(t0 + 1) * 256 + lane * 4, o);
    }

    // ---- sc consume: hpre = HSK + sum_k wn_k P1[s_k]; H = gelu(hpre) ----
    float hA = h2f(hsA), hB = h2f(hsB);
    #pragma unroll
    for (int k = 0; k < KNN; ++k) {
        float wkA = __uint_as_float(__builtin_amdgcn_readlane(__float_as_uint(wn2), k));
        float wkB = __uint_as_float(__builtin_amdgcn_readlane(__float_as_uint(wn2), 8 + k));
        hA = fmaf(wkA, h2f(p[k]),     hA);
        hB = fmaf(wkB, h2f(p[8 + k]), hB);
    }
    hA = gelu_tanh(hA);
    hB = gelu_tanh(hB);

    // ---- GEMM2 via per-wave LDS transpose ----
    sH[wv][0][lane] = hA;
    sH[wv][1][lane] = hB;
    asm volatile("s_waitcnt lgkmcnt(0)" ::: "memory");
    __builtin_amdgcn_sched_barrier(0);

    {
        int s = lane & 31, th = lane >> 5;      // lane covers (target th, output s)
        float acc2 = 0.f;
        #pragma unroll 4
        for (int h4 = 0; h4 < 16; ++h4) {
            float4 hv = *(const float4*)&sH[wv][th][h4 * 4];   // broadcast (2 groups)
            float4 w4 = *(const float4*)&sW2T[s][h4 * 4];      // stride-65: conflict-free
            acc2 = fmaf(hv.x, w4.x, acc2);
            acc2 = fmaf(hv.y, w4.y, acc2);
            acc2 = fmaf(hv.z, w4.z, acc2);
            acc2 = fmaf(hv.w, w4.w, acc2);
        }
        float* osc = out + OUT_MV_ELEMS;
        __builtin_nontemporal_store(acc2 + sb2[s], &osc[(size_t)(t0 + th) * SSC + s]);
    }
}

// ---------------------------------------------------------------------------
// Fallback pair (ws too small): original f32 mv gather + full scalar kernel.
// ---------------------------------------------------------------------------
__global__ __launch_bounds__(256) void kBf_mv(
        const float* __restrict__ mv_src,
        const float* __restrict__ mv_skip,
        const float* __restrict__ pos_src,
        const float* __restrict__ pos_tgt,
        const int*   __restrict__ isrc,
        const float* __restrict__ W1_mv,
        const float* __restrict__ W2_mv,
        float* __restrict__ out) {
    __shared__ float sWeff[CMV + CSKIP][MVD];
    __shared__ float stage[4][256];
    int tid = threadIdx.x;
    for (int e = tid; e < (CMV + CSKIP) * MVD; e += 256) {
        int c = e >> 4, d = e & 15;
        float a = 0.f;
        #pragma unroll 8
        for (int h = 0; h < HID; ++h)
            a = fmaf(W1_mv[c * HID + h], W2_mv[h * MVD + d], a);
        sWeff[c][d] = a;
    }
    __syncthreads();

    int lane = tid & 63, wv = tid >> 6;
    int d = lane >> 2, q = lane & 3;
    float wcol[CMV + CSKIP];
    #pragma unroll
    for (int c = 0; c < CMV + CSKIP; ++c) wcol[c] = sWeff[c][d];

    int wid = (int)((blockIdx.x * blockDim.x + tid) >> 6);
    int nw  = (int)((gridDim.x * blockDim.x) >> 6);
    for (int t = wid; t < N_TGT; t += nw) {
        float w = 0.f; int src = 0;
        if (lane < KNN) {
            src = isrc[t * KNN + lane];
            float dx = pos_src[src * 3 + 0] - pos_tgt[t * 3 + 0];
            float dy = pos_src[src * 3 + 1] - pos_tgt[t * 3 + 1];
            float dz = pos_src[src * 3 + 2] - pos_tgt[t * 3 + 2];
            float d2 = fmaxf(dx * dx + dy * dy + dz * dz, 1e-16f);
            w = 1.0f / d2;
        }
        float denom = w;
        denom += __shfl_xor(denom, 1);
        denom += __shfl_xor(denom, 2);
        denom += __shfl_xor(denom, 4);
        denom = __shfl(denom, 0);
        float invd = 1.0f / denom;

        float4 acc = make_float4(0.f, 0.f, 0.f, 0.f);
        #pragma unroll
        for (int k = 0; k < KNN; ++k) {
            int   sk = __builtin_amdgcn_readlane(src, k);
            float wk = __uint_as_float(__builtin_amdgcn_readlane(__float_as_uint(w), k));
            float4 v = *(const float4*)(mv_src + (size_t)sk * 256 + lane * 4);
            acc.x = fmaf(wk, v.x, acc.x);
            acc.y = fmaf(wk, v.y, acc.y);
            acc.z = fmaf(wk, v.z, acc.z);
            acc.w = fmaf(wk, v.w, acc.w);
        }
        asm volatile("" ::: "memory");
        *(float4*)&stage[wv][lane * 4] = acc;
        asm volatile("s_waitcnt lgkmcnt(0)" ::: "memory");
        __builtin_amdgcn_sched_barrier(0);

        float4 o = make_float4(0.f, 0.f, 0.f, 0.f);
        #pragma unroll
        for (int c = 0; c < CMV; ++c) {
            float4 v = *(const float4*)&stage[wv][c * 16 + q * 4];
            o.x = fmaf(v.x, wcol[c], o.x);
            o.y = fmaf(v.y, wcol[c], o.y);
            o.z = fmaf(v.z, wcol[c], o.z);
            o.w = fmaf(v.w, wcol[c], o.w);
        }
        const float4 u0 = *(const float4*)(mv_skip + (size_t)t * 32 + q * 4);
        const float4 u1 = *(const float4*)(mv_skip + (size_t)t * 32 + 16 + q * 4);
        float4 r;
        r.x = fmaf(o.x, invd, fmaf(wcol[16], u0.x, wcol[17] * u1.x));
        r.y = fmaf(o.y, invd, fmaf(wcol[16], u0.y, wcol[17] * u1.y));
        r.z = fmaf(o.z, invd, fmaf(wcol[16], u0.z, wcol[17] * u1.z));
        r.w = fmaf(o.w, invd, fmaf(wcol[16], u0.w, wcol[17] * u1.w));
        *(float4*)(out + (size_t)t * 256 + lane * 4) = r;
    }
}

__global__ __launch_bounds__(256) void kC_scalar(
        const float* __restrict__ sc_src,
        const float* __restrict__ sc_skip,
        const float* __restrict__ pos_src,
        const float* __restrict__ pos_tgt,
        const int*   __restrict__ isrc,
        const float* __restrict__ W1_s,
        const float* __restrict__ b1_s,
        const float* __restrict__ W2_s,
        const float* __restrict__ b2_s,
        float* __restrict__ out) {
    __shared__ float sW1[HID * HID];
    __shared__ float sW2T[SSC][68];
    __shared__ float sXT[HID][68];
    __shared__ float sH[64][68];
    __shared__ float swgt[64][9];
    __shared__ int   ssrcl[64][9];
    __shared__ float sb1[HID], sb2[SSC];

    int tid = threadIdx.x;
    #pragma unroll
    for (int r = 0; r < 4; ++r) {
        float4 v = *(const float4*)(W1_s + (r * 256 + tid) * 4);
        *(float4*)&sW1[(r * 256 + tid) * 4] = v;
    }
    for (int e = tid; e < HID * SSC; e += 256) {
        int h = e >> 5, s = e & 31;
        sW2T[s][h] = W2_s[e];
    }
    if (tid < HID) sb1[tid] = b1_s[tid];
    else if (tid < HID + SSC) sb2[tid - HID] = b2_s[tid - HID];

    int t0 = blockIdx.x * 64;
    if (tid < 64) {
        int t = t0 + tid;
        int4 e0 = *(const int4*)(isrc + t * KNN);
        int4 e1 = *(const int4*)(isrc + t * KNN + 4);
        int sk[KNN] = {e0.x, e0.y, e0.z, e0.w, e1.x, e1.y, e1.z, e1.w};
        float wkn[KNN];
        float ptx = pos_tgt[t * 3 + 0], pty = pos_tgt[t * 3 + 1], ptz = pos_tgt[t * 3 + 2];
        float den = 0.f;
        #pragma unroll
        for (int k = 0; k < KNN; ++k) {
            int s = sk[k];
            float dx = pos_src[s * 3 + 0] - ptx;
            float dy = pos_src[s * 3 + 1] - pty;
            float dz = pos_src[s * 3 + 2] - ptz;
            float d2 = fmaxf(dx * dx + dy * dy + dz * dz, 1e-16f);
            wkn[k] = 1.0f / d2;
            den += wkn[k];
        }
        float invd = 1.0f / den;
        #pragma unroll
        for (int k = 0; k < KNN; ++k) {
            swgt[tid][k]  = wkn[k] * invd;
            ssrcl[tid][k] = sk[k];
        }
    }
    __syncthreads();

    {
        int wv = tid >> 6, lane = tid & 63;
        int k = lane >> 3;
        int m = lane & 7;
        for (int i = 0; i < 16; i += 4) {
            int tb = wv * 16 + i;
            float4 v[4]; float wn4[4];
            #pragma unroll
            for (int j = 0; j < 4; ++j) {
                int tl = tb + j;
                wn4[j] = swgt[tl][k];
                int sk = ssrcl[tl][k];
                v[j] = *(const float4*)(sc_src + (size_t)sk * SSC + m * 4);
            }
            float4 u;
            if (lane < 32)
                u = *(const float4*)(sc_skip + (size_t)(t0 + tb + k) * SSC + m * 4);
            #pragma unroll
            for (int j = 0; j < 4; ++j) {
                float4 a = v[j]; float wnj = wn4[j];
                a.x *= wnj; a.y *= wnj; a.z *= wnj; a.w *= wnj;
                #pragma unroll
                for (int sft = 8; sft <= 32; sft <<= 1) {
                    a.x += __shfl_xor(a.x, sft);
                    a.y += __shfl_xor(a.y, sft);
                    a.z += __shfl_xor(a.z, sft);
                    a.w += __shfl_xor(a.w, sft);
                }
                if (lane < 8) {
                    sXT[4 * lane + 0][tb + j] = a.x;
                    sXT[4 * lane + 1][tb + j] = a.y;
                    sXT[4 * lane + 2][tb + j] = a.z;
                    sXT[4 * lane + 3][tb + j] = a.w;
                }
            }
            if (lane < 32) {
                sXT[SSC + 4 * m + 0][tb + k] = u.x;
                sXT[SSC + 4 * m + 1][tb + k] = u.y;
                sXT[SSC + 4 * m + 2][tb + k] = u.z;
                sXT[SSC + 4 * m + 3][tb + k] = u.w;
            }
        }
    }
    __syncthreads();

    int wv = tid >> 6;
    int lane = tid & 63;
    int tr4 = lane >> 4;
    int hc  = lane & 15;
    int tbase = wv * 16 + tr4 * 4;
    float acc[4][4];
    #pragma unroll
    for (int i = 0; i < 4; ++i)
        #pragma unroll
        for (int j = 0; j < 4; ++j) acc[i][j] = 0.f;

    #pragma unroll 2
    for (int c = 0; c < HID; ++c) {
        float4 xv = *(const float4*)&sXT[c][tbase];
        float4 wv4 = *(const float4*)&sW1[c * HID + hc * 4];
        acc[0][0] = fmaf(xv.x, wv4.x, acc[0][0]);
        acc[0][1] = fmaf(xv.x, wv4.y, acc[0][1]);
        acc[0][2] = fmaf(xv.x, wv4.z, acc[0][2]);
        acc[0][3] = fmaf(xv.x, wv4.w, acc[0][3]);
        acc[1][0] = fmaf(xv.y, wv4.x, acc[1][0]);
        acc[1][1] = fmaf(xv.y, wv4.y, acc[1][1]);
        acc[1][2] = fmaf(xv.y, wv4.z, acc[1][2]);
        acc[1][3] = fmaf(xv.y, wv4.w, acc[1][3]);
        acc[2][0] = fmaf(xv.z, wv4.x, acc[2][0]);
        acc[2][1] = fmaf(xv.z, wv4.y, acc[2][1]);
        acc[2][2] = fmaf(xv.z, wv4.z, acc[2][2]);
        acc[2][3] = fmaf(xv.z, wv4.w, acc[2][3]);
        acc[3][0] = fmaf(xv.w, wv4.x, acc[3][0]);
        acc[3][1] = fmaf(xv.w, wv4.y, acc[3][1]);
        acc[3][2] = fmaf(xv.w, wv4.z, acc[3][2]);
        acc[3][3] = fmaf(xv.w, wv4.w, acc[3][3]);
    }
    {
        float b0 = sb1[hc * 4 + 0], b1 = sb1[hc * 4 + 1];
        float b2 = sb1[hc * 4 + 2], b3 = sb1[hc * 4 + 3];
        #pragma unroll
        for (int i = 0; i < 4; ++i) {
            float4 hv;
            hv.x = gelu_tanh(acc[i][0] + b0);
            hv.y = gelu_tanh(acc[i][1] + b1);
            hv.z = gelu_tanh(acc[i][2] + b2);
            hv.w = gelu_tanh(acc[i][3] + b3);
            *(float4*)&sH[tbase + i][hc * 4] = hv;
        }
    }
    __syncthreads();

    int sc16 = lane & 15;
    float acc2[4][2];
    #pragma unroll
    for (int i = 0; i < 4; ++i) { acc2[i][0] = 0.f; acc2[i][1] = 0.f; }
    #pragma unroll 2
    for (int hh = 0; hh < 16; ++hh) {
        float4 wa = *(const float4*)&sW2T[sc16 * 2 + 0][hh * 4];
        float4 wb = *(const float4*)&sW2T[sc16 * 2 + 1][hh * 4];
        #pragma unroll
        for (int i = 0; i < 4; ++i) {
            float4 hv = *(const float4*)&sH[tbase + i][hh * 4];
            acc2[i][0] = fmaf(hv.x, wa.x, acc2[i][0]);
            acc2[i][0] = fmaf(hv.y, wa.y, acc2[i][0]);
            acc2[i][0] = fmaf(hv.z, wa.z, acc2[i][0]);
            acc2[i][0] = fmaf(hv.w, wa.w, acc2[i][0]);
            acc2[i][1] = fmaf(hv.x, wb.x, acc2[i][1]);
            acc2[i][1] = fmaf(hv.y, wb.y, acc2[i][1]);
            acc2[i][1] = fmaf(hv.z, wb.z, acc2[i][1]);
            acc2[i][1] = fmaf(hv.w, wb.w, acc2[i][1]);
        }
    }
    float* osc = out + OUT_MV_ELEMS;
    float bb0 = sb2[sc16 * 2 + 0], bb1 = sb2[sc16 * 2 + 1];
    #pragma unroll
    for (int i = 0; i < 4; ++i) {
        int t = t0 + tbase + i;
        float2 r = make_float2(acc2[i][0] + bb0, acc2[i][1] + bb1);
        *(float2*)&osc[(size_t)t * SSC + sc16 * 2] = r;
    }
}

// ---------------------------------------------------------------------------
extern "C" void kernel_launch(void* const* d_in, const int* in_sizes, int n_in,
                              void* d_out, int out_size, void* d_ws, size_t ws_size,
                              hipStream_t stream) {
    const float* mv_src   = (const float*)d_in[0];
    const float* mv_skip  = (const float*)d_in[1];
    const float* sc_src   = (const float*)d_in[2];
    const float* sc_skip  = (const float*)d_in[3];
    const float* pos_src  = (const float*)d_in[4];
    const float* pos_tgt  = (const float*)d_in[5];
    const int*   isrc     = (const int*)d_in[6];
    // d_in[7] = interp_target: structurally repeat(arange(N_TGT), K) -- unused
    const float* W1_mv    = (const float*)d_in[8];
    const float* W2_mv    = (const float*)d_in[9];
    const float* W1_s     = (const float*)d_in[10];
    const float* b1_s     = (const float*)d_in[11];
    const float* W2_s     = (const float*)d_in[12];
    const float* b2_s     = (const float*)d_in[13];
    float* out = (float*)d_out;
    float* ws  = (float*)d_ws;

    size_t need_ws_bytes = (size_t)WS_END * sizeof(float);
    if (ws_size >= need_ws_bytes) {
        hipLaunchKernelGGL(kA_preproject, dim3(2048), dim3(256), 0, stream,
                           mv_src, sc_src, sc_skip, pos_src, pos_tgt, isrc,
                           W1_mv, W2_mv, W1_s, b1_s, ws);
        hipLaunchKernelGGL(kFused, dim3(8192), dim3(256), 0, stream,
                           ws, mv_skip, isrc, W2_s, b2_s, out);
    } else {
        hipLaunchKernelGGL(kBf_mv, dim3(2048), dim3(256), 0, stream,
                           mv_src, mv_skip, pos_src, pos_tgt, isrc, W1_mv, W2_mv, out);
        hipLaunchKernelGGL(kC_scalar, dim3(N_TGT / 64), dim3(256), 0, stream,
                           sc_src, sc_skip, pos_src, pos_tgt, isrc,
                           W1_s, b1_s, W2_s, b2_s, out);
    }
}